// Round 3
// baseline (338.497 us; speedup 1.0000x reference)
//
#include <hip/hip_runtime.h>
#include <cstdint>
#include <cstddef>

// ---- problem constants ----
#define B_N     2
#define L_N     2048
#define DMODEL  512
#define DINNER  1024
#define DSTATE  64
#define NHEADS  16
#define EPROJ   2192      // 2*DINNER + 2*DSTATE + NHEADS
#define PB      2176      // bf16 proj row stride (z,x,B,C)
#define OFF_Z   0
#define OFF_XP  1024
#define OFF_B   2048
#define OFF_C   2112
#define LC      64        // scan chunk length (= matmul tile)
#define NC      32        // L_N / LC
#define MROWS   4096      // B_N * L_N
#define NBLK    512       // grid size (2 blocks/CU exactly — LDS-capped)

typedef unsigned short u16;
typedef unsigned int   u32;
typedef __attribute__((ext_vector_type(8))) short short8;   // 8 bf16 (4 VGPRs)
typedef __attribute__((ext_vector_type(4))) float floatx4;  // MFMA acc

__device__ __forceinline__ float silu_f(float v) { return v / (1.f + __expf(-v)); }

__device__ __forceinline__ u16 f2bf(float f) {
    union { float f; uint32_t u; } v; v.f = f;
    uint32_t r = (v.u + 0x7FFFu + ((v.u >> 16) & 1u)) >> 16;  // RNE
    return (u16)r;
}

__device__ __forceinline__ float bf2f(u16 b) {
    union { u32 u; float f; } v; v.u = (u32)b << 16; return v.f;
}

__device__ __forceinline__ u32 pack2(float lo, float hi) {
    return (u32)f2bf(lo) | ((u32)f2bf(hi) << 16);
}

__device__ __forceinline__ float lane_bcast(float v, int n) {
    union { float f; uint32_t u; } a, b;
    a.f = v;
    b.u = __builtin_amdgcn_readlane(a.u, n);
    return b.f;
}

// read bf16 fragment A[row][k0..k0+7] from pair-packed LDS tile (stride 33 dwords)
__device__ __forceinline__ short8 frag_ld(const u32* s, int row, int k0) {
    const u32* q = s + row * 33 + (k0 >> 1);
    union { u32 u[4]; short8 v; } r;
    r.u[0] = q[0]; r.u[1] = q[1]; r.u[2] = q[2]; r.u[3] = q[3];
    return r.v;
}

__device__ __forceinline__ void gload_lds16(const u16* g, u16* s) {
    __builtin_amdgcn_global_load_lds(
        (const __attribute__((address_space(1))) void*)g,
        (__attribute__((address_space(3))) void*)s,
        16, 0, 0);
}

// =====================================================================
// Manual grid barrier (agent scope). All NBLK blocks are co-resident
// (LDS 73.7 KB -> exactly 2 blocks/CU; grid == capacity), so spinning is
// deadlock-free. RELEASE fence flushes this XCD's L2 (cross-XCD vis),
// ACQUIRE fence invalidates L1+L2 before consuming other blocks' data.
// Counter is memset to 0 on the stream before each launch; targets are
// monotone NBLK*phase.
// =====================================================================
__device__ __forceinline__ void grid_bar(u32* cnt, u32 tgt) {
    __syncthreads();
    if (threadIdx.x == 0) {
        __builtin_amdgcn_fence(__ATOMIC_RELEASE, "agent");
        __hip_atomic_fetch_add(cnt, 1u, __ATOMIC_RELAXED, __HIP_MEMORY_SCOPE_AGENT);
        while (__hip_atomic_load(cnt, __ATOMIC_RELAXED, __HIP_MEMORY_SCOPE_AGENT) < tgt)
            __builtin_amdgcn_s_sleep(2);
        __builtin_amdgcn_fence(__ATOMIC_ACQUIRE, "agent");
    }
    __syncthreads();
}

// =====================================================================
// bf16 MFMA GEMM body, 2-phase double-buffered.
//   C = A[M,K] @ Bt[N,K]^T.  4 waves as 2x2; wave tile (BM/2)x(BN/2).
// K % (32*NPB) == 0 assumed. PSPLIT: col<2176 -> bf16 projb; else f32 dtT
// (TRANSPOSED [h][row] so phase1 reads dt coalesced).
// LDS: 2*NPB*(BM+BN)*64 B  (gemm1 NPB=2: 73.7 KB; gemm2 NPB=4: 65.5 KB).
// =====================================================================
template<int BM, int BN, int NPB, bool GUARD, bool PSPLIT>
__device__ __forceinline__ void gemm_body(char* smemc, int bx, int by,
    const u16* __restrict__ A, const u16* __restrict__ Bt,
    float* __restrict__ Cf, u16* __restrict__ Cb, float* __restrict__ Dt,
    int M, int N, int K)
{
    constexpr int MI = BM / 32;
    constexpr int NI = BN / 32;
    constexpr int KB = 32 * NPB;
    u16* AsBase = (u16*)smemc;                                   // [2][NPB][BM*32]
    u16* BsBase = (u16*)(smemc + (size_t)2 * NPB * BM * 32 * 2); // [2][NPB][BN*32]

    const int tid = threadIdx.x;
    const int w   = tid >> 6;
    const int ln  = tid & 63;
    const int wm  = w >> 1, wn = w & 1;
    const int bm  = by * BM;
    const int bn  = bx * BN;

    const int srow = ln >> 2;          // 16 rows per wave-load group
    const int skq  = (ln & 3) * 8;
    const int fr = ln & 15;
    const int fq = (ln >> 4) * 8;

    floatx4 acc[MI][NI];
    const floatx4 fzero = {0.f, 0.f, 0.f, 0.f};
    #pragma unroll
    for (int mi = 0; mi < MI; ++mi)
        #pragma unroll
        for (int ni = 0; ni < NI; ++ni) acc[mi][ni] = fzero;

    auto As = [&](int buf, int p) -> u16* {
        return AsBase + ((size_t)buf * NPB + p) * (BM * 32);
    };
    auto Bs = [&](int buf, int p) -> u16* {
        return BsBase + ((size_t)buf * NPB + p) * (BN * 32);
    };

    auto stage = [&](int buf, int k0) {
        #pragma unroll
        for (int p = 0; p < NPB; ++p) {
            const int kp = k0 + p * 32;
            #pragma unroll
            for (int g = 0; g < BM / 16; ++g) {
                if ((g & 3) != w) continue;    // group -> wave round-robin
                gload_lds16(A + (size_t)(bm + g * 16 + srow) * K + kp + skq,
                            As(buf, p) + g * 16 * 32);
            }
            #pragma unroll
            for (int g = 0; g < BN / 16; ++g) {
                if ((g & 3) != w) continue;
                int rn = bn + g * 16 + srow;
                if (GUARD) rn = (rn < N) ? rn : (N - 1);
                gload_lds16(Bt + (size_t)rn * K + kp + skq,
                            Bs(buf, p) + g * 16 * 32);
            }
        }
    };

    auto compute = [&](int buf) {
        #pragma unroll
        for (int p = 0; p < NPB; ++p) {
            short8 af[MI], bfv[NI];
            #pragma unroll
            for (int mi = 0; mi < MI; ++mi)
                af[mi] = *(const short8*)&As(buf, p)[(wm * (BM / 2) + mi * 16 + fr) * 32 + fq];
            #pragma unroll
            for (int ni = 0; ni < NI; ++ni)
                bfv[ni] = *(const short8*)&Bs(buf, p)[(wn * (BN / 2) + ni * 16 + fr) * 32 + fq];
            #pragma unroll
            for (int mi = 0; mi < MI; ++mi)
                #pragma unroll
                for (int ni = 0; ni < NI; ++ni)
                    acc[mi][ni] = __builtin_amdgcn_mfma_f32_16x16x32_bf16(
                        af[mi], bfv[ni], acc[mi][ni], 0, 0, 0);
        }
    };

    // ---- prologue ----
    stage(0, 0);
    __syncthreads();                     // drains vmcnt(0): buf0 ready

    // ---- 2-phase main loop: prefetch(next) overlaps compute(cur) ----
    int cur = 0;
    for (int k0 = 0; k0 + KB < K; k0 += KB) {
        stage(cur ^ 1, k0 + KB);         // issue next-tile loads FIRST
        compute(cur);                    // MFMAs hide the load latency
        __syncthreads();                 // one vmcnt+lgkm drain + barrier per tile
        cur ^= 1;
    }
    compute(cur);                        // last tile, registers only afterwards

    const int cr = (ln >> 4) * 4;
    const int cc = ln & 15;
    #pragma unroll
    for (int mi = 0; mi < MI; ++mi) {
        const int row0 = bm + wm * (BM / 2) + mi * 16 + cr;
        #pragma unroll
        for (int ni = 0; ni < NI; ++ni) {
            const int col = bn + wn * (BN / 2) + ni * 16 + cc;
            #pragma unroll
            for (int r = 0; r < 4; ++r) {
                const int row = row0 + r;
                const float v = acc[mi][ni][r];
                if (PSPLIT) {
                    if (col < PB)
                        Cb[(size_t)row * PB + col] = f2bf(v);
                    else if (col < EPROJ)
                        Dt[(size_t)(col - PB) * MROWS + row] = v;   // TRANSPOSED [h][row]
                } else {
                    Cf[(size_t)row * N + col] = v;
                }
            }
        }
    }
}

// =====================================================================
// SSD phase 1 body — 4-wave cooperative per virtual (b,h,chunk):
//   conv+silu via register sliding window over DIRECT global x reads;
//   exports conv'd X^T. La = cumsum(logdA);
//   Hc = (e^(La63-La_s) B)^T @ X (MFMA) -> stored bf16 (hb).
// =====================================================================
__device__ void p1_body(char* smemc, int bid,
    const u16* __restrict__ projb, const float* __restrict__ dtf,
    const float* __restrict__ cw, const float* __restrict__ cb,
    const float* __restrict__ A_log, const float* __restrict__ dt_bias,
    u16* __restrict__ hb, float* __restrict__ Pc, float* __restrict__ LaBuf,
    u32* __restrict__ xT)
{
    u32* sBD = (u32*)smemc;             // 64*33 u32 = 8448 B
    u32* sXt = (u32*)(smemc + 8448);    // 8448 B

    const int c = bid & (NC - 1);
    const int h = (bid >> 5) & (NHEADS - 1);
    const int b = bid >> 9;
    const int tid = threadIdx.x;
    const int w = tid >> 6, ln = tid & 63;
    const int a = ln & 15, q = ln >> 4;
    const size_t r0 = (size_t)b * L_N + c * LC;

    // logdA + inclusive cumsum (redundant per wave; all waves identical)
    // dtf is [h][row] (transposed in gemm1 epilogue) -> coalesced 256 B read
    float dt = dtf[(size_t)h * MROWS + r0 + ln] + dt_bias[h];
    float sp = (dt > 15.f) ? dt : log1pf(__expf(dt));
    float La = sp * (-__expf(A_log[h]));
    #pragma unroll
    for (int d = 1; d < 64; d <<= 1) {
        float up = __shfl_up(La, d, 64);
        if (ln >= d) La += up;
    }
    if (w == 0) LaBuf[(size_t)bid * 64 + ln] = La;
    const float La63 = lane_bcast(La, 63);

    const int ch = h * 64 + ln;
    const float4 w4 = *(const float4*)(cw + ch * 4);
    const float bias = cb[ch];
    const u16* xcol = projb + OFF_XP + ch;     // column base for x reads
    const size_t bbase = (size_t)b * L_N;

    // rolling window: xr[0..2] = x at local rows (s-3, s-2, s-1); s0 = 16w
    float xr[3];
    #pragma unroll
    for (int i = 0; i < 3; ++i) {
        const int tl = c * LC + 16 * w - 3 + i;
        xr[i] = (tl >= 0) ? bf2f(xcol[(bbase + tl) * PB]) : 0.f;
    }

    // staging: wave w covers s-pairs [w*8, w*8+8); conv+silu inline
    #pragma unroll
    for (int j = 0; j < 8; ++j) {
        const int sp_ = w * 8 + j, s = sp_ * 2;
        const float xa = bf2f(xcol[(r0 + s) * PB]);
        const float xb = bf2f(xcol[(r0 + s + 1) * PB]);
        float a0 = bias, a1 = bias;
        a0 += xr[0] * w4.x; a0 += xr[1] * w4.y; a0 += xr[2] * w4.z; a0 += xa * w4.w;
        a1 += xr[1] * w4.x; a1 += xr[2] * w4.y; a1 += xa * w4.z;   a1 += xb * w4.w;
        xr[0] = xr[2]; xr[1] = xa; xr[2] = xb;
        const float x0 = silu_f(a0), x1 = silu_f(a1);
        const u32 xp = pack2(x0, x1);
        sXt[ln * 33 + sp_] = xp;
        xT[(size_t)bid * 2048 + sp_ * 64 + ln] = xp;   // export for phase3
        const float w0 = __expf(La63 - lane_bcast(La, s));
        const float w1 = __expf(La63 - lane_bcast(La, s + 1));
        const float b0 = bf2f(projb[(r0 + s) * PB + OFF_B + ln]) * w0;
        const float b1 = bf2f(projb[(r0 + s + 1) * PB + OFF_B + ln]) * w1;
        sBD[ln * 33 + sp_] = pack2(b0, b1);
    }
    __syncthreads();

    // MFMA: wave w computes output tile-row tm=w (rows n in [16w,16w+16))
    short8 af[2], bf[4][2];
    #pragma unroll
    for (int ks = 0; ks < 2; ++ks)
        af[ks] = frag_ld(sBD, w * 16 + a, ks * 32 + q * 8);
    #pragma unroll
    for (int tn = 0; tn < 4; ++tn)
        #pragma unroll
        for (int ks = 0; ks < 2; ++ks)
            bf[tn][ks] = frag_ld(sXt, tn * 16 + a, ks * 32 + q * 8);

    const floatx4 fzero = {0.f, 0.f, 0.f, 0.f};
    floatx4 acc[4];
    #pragma unroll
    for (int tn = 0; tn < 4; ++tn) {
        acc[tn] = fzero;
        #pragma unroll
        for (int ks = 0; ks < 2; ++ks)
            acc[tn] = __builtin_amdgcn_mfma_f32_16x16x32_bf16(
                af[ks], bf[tn][ks], acc[tn], 0, 0, 0);
    }

    u16* hp = hb + (size_t)bid * 4096;         // Hc bf16 [n][p]
    #pragma unroll
    for (int tn = 0; tn < 4; ++tn)
        #pragma unroll
        for (int r = 0; r < 4; ++r)
            hp[(w * 16 + q * 4 + r) * 64 + tn * 16 + a] = f2bf(acc[tn][r]);
    if (tid == 0) Pc[bid] = __expf(La63);
    __syncthreads();   // safe LDS reuse on next virtual iteration
}

// =====================================================================
// SSD phase 2 body — element-parallel inter-chunk carry over bf16
// h-state (u32 pairs, f32 carries). Active on blocks [0,256) only.
// =====================================================================
__device__ void p2_body(int bid, int tid,
    u32* __restrict__ hb32, const float* __restrict__ Pc)
{
    const int bh = bid >> 3;
    const int e = (bid & 7) * 256 + tid;            // u32 pair 0..2047
    const size_t base = (size_t)(bh * NC) * 2048 + e;

    u32 v[NC];
    #pragma unroll
    for (int c = 0; c < NC; ++c)
        v[c] = hb32[base + (size_t)c * 2048];

    float c0 = 0.f, c1 = 0.f;
    #pragma unroll
    for (int c = 0; c < NC; ++c) {
        const u32 cur = v[c];
        const float lo = bf2f((u16)cur), hi = bf2f((u16)(cur >> 16));
        v[c] = pack2(c0, c1);                  // h_start entering chunk c
        const float Pv = Pc[bh * NC + c];
        c0 = fmaf(Pv, c0, lo);
        c1 = fmaf(Pv, c1, hi);
    }

    #pragma unroll
    for (int c = 0; c < NC; ++c)
        hb32[base + (size_t)c * 2048] = v[c];
}

// =====================================================================
// SSD phase 3 body — per virtual (b,h,chunk):
//   X^T precomputed (phase1); h_start bf16 (phase2);
//   S^T = B @ C;  W[i][s] = S[i,s] e^(La_i-La_s) (s<=i)
//   Y = diag(e^La) C @ h_start^T + W @ X^T;  yz = Y * silu(z)
// =====================================================================
__device__ void p3_body(char* lds, int bid,
    const u16* __restrict__ projb, const u32* __restrict__ xT,
    const u16* __restrict__ hb, const float* __restrict__ LaBuf,
    u16* __restrict__ yz)
{
    u32* sBW   = (u32*)lds;              // B natural, then W (aliased)
    u32* sC    = (u32*)(lds + 8448);     // C natural [i][n-pair]
    u32* sXt   = (u32*)(lds + 16896);    // X^T [p][s-pair]
    u32* sH    = (u32*)(lds + 25344);    // h_start^T [p][n-pair]
    float* sLaF = (float*)(lds + 33792); // La[64]
    float* sY  = (float*)(lds + 8448);   // f32 [i][p] 64x66, aliases sC+sXt (epilogue)

    const int c = bid & (NC - 1);
    const int h = (bid >> 5) & (NHEADS - 1);
    const int b = bid >> 9;
    const int tid = threadIdx.x;
    const int w = tid >> 6, ln = tid & 63;
    const int a = ln & 15, q = ln >> 4;
    const int hw = ln >> 5, k32 = ln & 31;
    const size_t r0 = (size_t)b * L_N + c * LC;

    if (tid < 64) sLaF[tid] = LaBuf[(size_t)bid * 64 + tid];

    // single staging pass: B, C natural (raw copies); X^T copy; H^T pack
    const u16* hs = hb + (size_t)bid * 4096;
    #pragma unroll
    for (int j = 0; j < 8; ++j) {
        const int rp = w * 8 + j;
        const int row = rp * 2 + hw;
        sBW[row * 33 + k32] = *(const u32*)(projb + (r0 + row) * PB + OFF_B + 2 * k32);
        sC [row * 33 + k32] = *(const u32*)(projb + (r0 + row) * PB + OFF_C + 2 * k32);
        sXt[ln * 33 + rp] = xT[(size_t)bid * 2048 + rp * 64 + ln];
        sH [ln * 33 + rp] = (u32)hs[(2 * rp) * 64 + ln]
                          | ((u32)hs[(2 * rp + 1) * 64 + ln] << 16);
    }
    __syncthreads();

    const floatx4 fzero = {0.f, 0.f, 0.f, 0.f};

    // ---- m1: S^T tiles [tm][tn=w], tm<=w ----
    short8 cfr[2], bfr[4][2];
    #pragma unroll
    for (int ks = 0; ks < 2; ++ks)
        cfr[ks] = frag_ld(sC, w * 16 + a, ks * 32 + q * 8);
    #pragma unroll
    for (int tm = 0; tm < 4; ++tm)
        if (tm <= w)
            #pragma unroll
            for (int ks = 0; ks < 2; ++ks)
                bfr[tm][ks] = frag_ld(sBW, tm * 16 + a, ks * 32 + q * 8);
    floatx4 accS[4];
    #pragma unroll
    for (int tm = 0; tm < 4; ++tm) {
        if (tm > w) continue;
        accS[tm] = fzero;
        #pragma unroll
        for (int ks = 0; ks < 2; ++ks)
            accS[tm] = __builtin_amdgcn_mfma_f32_16x16x32_bf16(
                bfr[tm][ks], cfr[ks], accS[tm], 0, 0, 0);
    }
    __syncthreads();   // all waves done reading B before W overwrite

    // ---- build W rows i in [16w,16w+16) ----
    {
        const int i = w * 16 + a;
        const float Li = sLaF[i];
        #pragma unroll
        for (int tm = 0; tm < 4; ++tm) {
            const int d0 = i * 33 + tm * 8 + q * 2;
            if (tm > w) {
                sBW[d0] = 0; sBW[d0 + 1] = 0;
            } else {
                const float4 Ls = *(const float4*)(sLaF + tm * 16 + q * 4);
                float v[4];
                #pragma unroll
                for (int r = 0; r < 4; ++r) {
                    const int s = tm * 16 + q * 4 + r;
                    const float ww = (s <= i) ? __expf(Li - ((const float*)&Ls)[r]) : 0.f;
                    v[r] = accS[tm][r] * ww;
                }
                sBW[d0]     = pack2(v[0], v[1]);
                sBW[d0 + 1] = pack2(v[2], v[3]);
            }
        }
    }

    // ---- m4: accY = C @ h_start^T (row-tile w), scale rows by e^La_i ----
    short8 hfr[4][2];
    #pragma unroll
    for (int tp = 0; tp < 4; ++tp)
        #pragma unroll
        for (int ks = 0; ks < 2; ++ks)
            hfr[tp][ks] = frag_ld(sH, tp * 16 + a, ks * 32 + q * 8);
    floatx4 accY[4];
    #pragma unroll
    for (int tp = 0; tp < 4; ++tp) {
        accY[tp] = fzero;
        #pragma unroll
        for (int ks = 0; ks < 2; ++ks)
            accY[tp] = __builtin_amdgcn_mfma_f32_16x16x32_bf16(
                cfr[ks], hfr[tp][ks], accY[tp], 0, 0, 0);
    }
    {
        const float4 Ls = *(const float4*)(sLaF + w * 16 + q * 4);
        float e4[4];
        #pragma unroll
        for (int r = 0; r < 4; ++r) e4[r] = __expf(((const float*)&Ls)[r]);
        #pragma unroll
        for (int tp = 0; tp < 4; ++tp)
            #pragma unroll
            for (int r = 0; r < 4; ++r) accY[tp][r] *= e4[r];
    }

    // ---- m2: accY += W @ X^T (wave reads only its own W rows) ----
    short8 wfr[2], xfr[4][2];
    #pragma unroll
    for (int ks = 0; ks < 2; ++ks)
        wfr[ks] = frag_ld(sBW, w * 16 + a, ks * 32 + q * 8);
    #pragma unroll
    for (int tp = 0; tp < 4; ++tp)
        #pragma unroll
        for (int ks = 0; ks < 2; ++ks)
            xfr[tp][ks] = frag_ld(sXt, tp * 16 + a, ks * 32 + q * 8);
    #pragma unroll
    for (int tp = 0; tp < 4; ++tp)
        #pragma unroll
        for (int ks = 0; ks < 2; ++ks)
            accY[tp] = __builtin_amdgcn_mfma_f32_16x16x32_bf16(
                wfr[ks], xfr[tp][ks], accY[tp], 0, 0, 0);
    __syncthreads();   // all frag reads of sC/sXt done; safe to alias as sY

    // ---- epilogue: own-rows LDS round-trip, gate (bf16 z), bf16 store ----
    #pragma unroll
    for (int tp = 0; tp < 4; ++tp)
        #pragma unroll
        for (int r = 0; r < 4; ++r)
            sY[(w * 16 + q * 4 + r) * 66 + tp * 16 + a] = accY[tp][r];
    #pragma unroll
    for (int ii = 0; ii < 16; ++ii) {
        const int i = w * 16 + ii;
        const float y = sY[i * 66 + ln];
        const float z = bf2f(projb[(r0 + i) * PB + OFF_Z + h * 64 + ln]);
        yz[(r0 + i) * DINNER + h * 64 + ln] = f2bf(y * silu_f(z));
    }
    __syncthreads();   // safe LDS reuse on next virtual iteration
}

// =====================================================================
// Mega kernel — the whole pipeline in one plain launch, phases separated
// by a manual agent-scope grid barrier.
// 512 blocks x 256 threads = exactly 2 blocks/CU (LDS 73.7 KB <= 80 KB
// per slot) => all blocks co-resident => spin barrier is safe.
// =====================================================================
struct MArgs {
    const float *x, *W_in, *conv_w, *conv_b, *A_log, *dt_bias, *W_out;
    float* out;
    u16* projb; float* dtf; u16* hb; float* Pc; float* LaBuf;
    u16 *xbf, *wibf, *wobf, *yzbf; u32* xT;
    u32* gbar;
};

__global__ __launch_bounds__(256, 2) void mega_kern(MArgs P)
{
    __shared__ char smem[73728];
    const int bid = blockIdx.x;
    const int tid = threadIdx.x;

    // ---- phase 0: fused fp32->bf16 casts (x, W_in, W_out) ----
    {
        const int n0 = MROWS * DMODEL / 4;
        const int n1 = EPROJ * DMODEL / 4;
        const int n2 = DMODEL * DINNER / 4;
        const int total = n0 + n1 + n2;
        for (int i = bid * 256 + tid; i < total; i += NBLK * 256) {
            const float* s; u16* d; int j = i;
            if (j < n0)      { s = P.x;    d = P.xbf; }
            else {
                j -= n0;
                if (j < n1)  { s = P.W_in; d = P.wibf; }
                else         { j -= n1; s = P.W_out; d = P.wobf; }
            }
            float4 v = ((const float4*)s)[j];
            ushort4 o;
            o.x = f2bf(v.x); o.y = f2bf(v.y); o.z = f2bf(v.z); o.w = f2bf(v.w);
            ((ushort4*)d)[j] = o;
        }
    }
    grid_bar(P.gbar, NBLK * 1);

    // ---- phase 1: in_proj GEMM (M=4096, N=2192, K=512); 448 tiles ----
    if (bid < 448)
        gemm_body<128, 160, 2, true, true>(smem, bid % 14, bid / 14,
            P.xbf, P.wibf, nullptr, P.projb, P.dtf, MROWS, EPROJ, DMODEL);
    grid_bar(P.gbar, NBLK * 2);

    // ---- phase 2: SSD p1, 1024 virtual blocks (2 per real block) ----
    #pragma unroll
    for (int it = 0; it < 2; ++it)
        p1_body(smem, bid * 2 + it, P.projb, P.dtf, P.conv_w, P.conv_b,
                P.A_log, P.dt_bias, P.hb, P.Pc, P.LaBuf, P.xT);
    grid_bar(P.gbar, NBLK * 3);

    // ---- phase 3: SSD p2 carry (blocks [0,256) active) ----
    if (bid < 256)
        p2_body(bid, tid, (u32*)P.hb, P.Pc);
    grid_bar(P.gbar, NBLK * 4);

    // ---- phase 4: SSD p3, 1024 virtual blocks ----
    #pragma unroll
    for (int it = 0; it < 2; ++it)
        p3_body(smem, bid * 2 + it, P.projb, P.xT, P.hb, P.LaBuf, P.yzbf);
    grid_bar(P.gbar, NBLK * 5);

    // ---- phase 5: out_proj GEMM (M=4096, N=512, K=1024); 512 tiles ----
    gemm_body<64, 64, 4, false, false>(smem, bid % 8, bid / 8,
        P.yzbf, P.wobf, P.out, nullptr, nullptr, MROWS, DMODEL, DINNER);
}

// =====================================================================
extern "C" void kernel_launch(void* const* d_in, const int* in_sizes, int n_in,
                              void* d_out, int out_size, void* d_ws, size_t ws_size,
                              hipStream_t stream)
{
    // workspace layout (~59 MB)
    u16*   projb = (u16*)d_ws;                                  // 4096*2176 bf16
    float* dtf   = (float*)(projb + (size_t)4096 * PB);         // 16*4096 f32 (TRANSPOSED [h][row])
    u16*   hb    = (u16*)(dtf + (size_t)4096 * 16);             // 1024*4096 bf16 (h-state)
    float* Pc    = (float*)(hb + (size_t)1024 * 4096);          // 1024
    float* LaBuf = Pc + 1024;                                   // 1024*64
    u16*   xbf   = (u16*)(LaBuf + 1024 * 64);                   // 4096*512 bf16
    u16*   wibf  = xbf + (size_t)4096 * DMODEL;                 // 2192*512 bf16
    u16*   wobf  = wibf + (size_t)EPROJ * DMODEL;               // 512*1024 bf16
    u16*   yzbf  = wobf + (size_t)DMODEL * DINNER;              // 4096*1024 bf16
    u32*   xT    = (u32*)(yzbf + (size_t)4096 * DINNER);        // 1024*2048 u32 (conv'd X^T)
    u32*   gbar  = xT + (size_t)1024 * 2048;                    // barrier counter (64 B)

    MArgs a;
    a.x       = (const float*)d_in[0];
    a.W_in    = (const float*)d_in[1];
    a.conv_w  = (const float*)d_in[2];
    a.conv_b  = (const float*)d_in[3];
    a.A_log   = (const float*)d_in[4];
    a.dt_bias = (const float*)d_in[5];
    a.W_out   = (const float*)d_in[6];
    a.out     = (float*)d_out;
    a.projb = projb; a.dtf = dtf; a.hb = hb; a.Pc = Pc; a.LaBuf = LaBuf;
    a.xbf = xbf; a.wibf = wibf; a.wobf = wobf; a.yzbf = yzbf; a.xT = xT;
    a.gbar = gbar;

    // zero the barrier counter every launch (captured in the graph, so
    // each replay resets it; survives workspace re-poison).
    hipMemsetAsync(gbar, 0, 64, stream);

    mega_kern<<<dim3(NBLK), dim3(256), 0, stream>>>(a);
}

// Round 4
// 133.267 us; speedup vs baseline: 2.5400x; 2.5400x over previous
//
#include <hip/hip_runtime.h>
#include <cstdint>
#include <cstddef>

// ---- problem constants ----
#define B_N     2
#define L_N     2048
#define DMODEL  512
#define DINNER  1024
#define DSTATE  64
#define NHEADS  16
#define EPROJ   2192      // 2*DINNER + 2*DSTATE + NHEADS
#define PB      2176      // bf16 proj row stride (z,x,B,C)
#define OFF_Z   0
#define OFF_XP  1024
#define OFF_B   2048
#define OFF_C   2112
#define LC      64        // scan chunk length (= matmul tile)
#define NC      32        // L_N / LC
#define MROWS   4096      // B_N * L_N

typedef unsigned short u16;
typedef unsigned int   u32;
typedef __attribute__((ext_vector_type(8))) short short8;   // 8 bf16 (4 VGPRs)
typedef __attribute__((ext_vector_type(4))) float floatx4;  // MFMA acc

__device__ __forceinline__ float silu_f(float v) { return v / (1.f + __expf(-v)); }

__device__ __forceinline__ u16 f2bf(float f) {
    union { float f; uint32_t u; } v; v.f = f;
    uint32_t r = (v.u + 0x7FFFu + ((v.u >> 16) & 1u)) >> 16;  // RNE
    return (u16)r;
}

__device__ __forceinline__ float bf2f(u16 b) {
    union { u32 u; float f; } v; v.u = (u32)b << 16; return v.f;
}

__device__ __forceinline__ u32 pack2(float lo, float hi) {
    return (u32)f2bf(lo) | ((u32)f2bf(hi) << 16);
}

// HW packed f32->bf16 (RNE), 2 elems/instr — for gemm1 inline cast staging
__device__ __forceinline__ u32 cvtpk(float lo, float hi) {
    u32 r;
    asm("v_cvt_pk_bf16_f32 %0, %1, %2" : "=v"(r) : "v"(lo), "v"(hi));
    return r;
}

__device__ __forceinline__ uint4 pk8(const float4& a, const float4& b) {
    uint4 o;
    o.x = cvtpk(a.x, a.y); o.y = cvtpk(a.z, a.w);
    o.z = cvtpk(b.x, b.y); o.w = cvtpk(b.z, b.w);
    return o;
}

__device__ __forceinline__ float lane_bcast(float v, int n) {
    union { float f; uint32_t u; } a, b;
    a.f = v;
    b.u = __builtin_amdgcn_readlane(a.u, n);
    return b.f;
}

// read bf16 fragment A[row][k0..k0+7] from pair-packed LDS tile (stride 33 dwords)
__device__ __forceinline__ short8 frag_ld(const u32* s, int row, int k0) {
    const u32* q = s + row * 33 + (k0 >> 1);
    union { u32 u[4]; short8 v; } r;
    r.u[0] = q[0]; r.u[1] = q[1]; r.u[2] = q[2]; r.u[3] = q[3];
    return r.v;
}

__device__ __forceinline__ void gload_lds16(const u16* g, u16* s) {
    __builtin_amdgcn_global_load_lds(
        (const __attribute__((address_space(1))) void*)g,
        (__attribute__((address_space(3))) void*)s,
        16, 0, 0);
}

// =====================================================================
// bf16 MFMA GEMM, 2-phase double-buffered.
//   C = A[M,K] @ Bt[N,K]^T.  4 waves as 2x2; wave tile (BM/2)x(BN/2).
// K % (32*NPB) == 0 assumed. PSPLIT: col<2176 -> bf16 projb; else f32 dtT
// (TRANSPOSED [h][row] so phase1 reads dt coalesced).
// CVTIN: A/Bt are fp32; staging inline-casts to bf16 (T14 split: issue
// loads -> compute(cur) -> cvt+ds_write -> barrier). Block-private tiles
// mean NO cross-block dependency => the standalone cast kernel vanishes.
// LDS: 2*NPB*(BM+BN)*64 B  (gemm1 NPB=2: 73.7 KB; gemm2 NPB=4: 65.5 KB —
// both exactly 2 blocks/CU).
// =====================================================================
template<int BM, int BN, int NPB, bool GUARD, bool PSPLIT, bool CVTIN>
__global__ __launch_bounds__(256, 2) void gemm_mfma_bt(
    const void* __restrict__ Av, const void* __restrict__ Btv,
    float* __restrict__ Cf, u16* __restrict__ Cb, float* __restrict__ Dt,
    int M, int N, int K)
{
    constexpr int MI = BM / 32;
    constexpr int NI = BN / 32;
    constexpr int KB = 32 * NPB;
    constexpr int NGA = BM / 64;              // A-groups per wave per panel
    constexpr int NGB = (BN / 16 + 3) / 4;    // B-groups per wave per panel (tail predicated)
    __shared__ u16 As_[2][NPB][BM * 32];
    __shared__ u16 Bs_[2][NPB][BN * 32];

    const int tid = threadIdx.x;
    const int w   = tid >> 6;
    const int ln  = tid & 63;
    const int wm  = w >> 1, wn = w & 1;
    const int bm  = blockIdx.y * BM;
    const int bn  = blockIdx.x * BN;

    const int srow = ln >> 2;          // 16 rows per wave-load group
    const int skq  = (ln & 3) * 8;
    const int fr = ln & 15;
    const int fq = (ln >> 4) * 8;

    floatx4 acc[MI][NI];
    const floatx4 fzero = {0.f, 0.f, 0.f, 0.f};
    #pragma unroll
    for (int mi = 0; mi < MI; ++mi)
        #pragma unroll
        for (int ni = 0; ni < NI; ++ni) acc[mi][ni] = fzero;

    auto compute = [&](int buf) {
        #pragma unroll
        for (int p = 0; p < NPB; ++p) {
            short8 af[MI], bfv[NI];
            #pragma unroll
            for (int mi = 0; mi < MI; ++mi)
                af[mi] = *(const short8*)&As_[buf][p][(wm * (BM / 2) + mi * 16 + fr) * 32 + fq];
            #pragma unroll
            for (int ni = 0; ni < NI; ++ni)
                bfv[ni] = *(const short8*)&Bs_[buf][p][(wn * (BN / 2) + ni * 16 + fr) * 32 + fq];
            #pragma unroll
            for (int mi = 0; mi < MI; ++mi)
                #pragma unroll
                for (int ni = 0; ni < NI; ++ni)
                    acc[mi][ni] = __builtin_amdgcn_mfma_f32_16x16x32_bf16(
                        af[mi], bfv[ni], acc[mi][ni], 0, 0, 0);
        }
    };

    if constexpr (CVTIN) {
        // ---------- fp32 inputs, inline-cast reg staging ----------
        const float* A  = (const float*)Av;
        const float* Bt = (const float*)Btv;
        float4 hA[NPB][NGA][2];
        float4 hB[NPB][NGB][2];

        auto ld = [&](int k0) {           // issue f32 loads into hold regs
            #pragma unroll
            for (int p = 0; p < NPB; ++p) {
                const int kp = k0 + p * 32;
                #pragma unroll
                for (int gi = 0; gi < NGA; ++gi) {
                    const int g = gi * 4 + w;
                    const float* s = A + (size_t)(bm + g * 16 + srow) * K + kp + skq;
                    hA[p][gi][0] = *(const float4*)s;
                    hA[p][gi][1] = *(const float4*)(s + 4);
                }
                #pragma unroll
                for (int gi = 0; gi < NGB; ++gi) {
                    const int g = gi * 4 + w;
                    if (g < BN / 16) {
                        int rn = bn + g * 16 + srow;
                        if (GUARD) rn = (rn < N) ? rn : (N - 1);
                        const float* s = Bt + (size_t)rn * K + kp + skq;
                        hB[p][gi][0] = *(const float4*)s;
                        hB[p][gi][1] = *(const float4*)(s + 4);
                    }
                }
            }
        };
        auto st = [&](int buf) {          // cvt + LDS write (waits loads here)
            #pragma unroll
            for (int p = 0; p < NPB; ++p) {
                #pragma unroll
                for (int gi = 0; gi < NGA; ++gi) {
                    const int g = gi * 4 + w;
                    ((uint4*)&As_[buf][p][g * 16 * 32])[ln] =
                        pk8(hA[p][gi][0], hA[p][gi][1]);
                }
                #pragma unroll
                for (int gi = 0; gi < NGB; ++gi) {
                    const int g = gi * 4 + w;
                    if (g < BN / 16)
                        ((uint4*)&Bs_[buf][p][g * 16 * 32])[ln] =
                            pk8(hB[p][gi][0], hB[p][gi][1]);
                }
            }
        };

        ld(0); st(0);
        __syncthreads();
        int cur = 0;
        for (int k0 = 0; k0 + KB < K; k0 += KB) {
            ld(k0 + KB);                 // issue next-tile f32 loads
            compute(cur);                // MFMAs hide the load latency
            st(cur ^ 1);                 // cvt+write after compute (T14)
            __syncthreads();
            cur ^= 1;
        }
        compute(cur);
    } else {
        // ---------- bf16 inputs, global_load_lds staging ----------
        const u16* A  = (const u16*)Av;
        const u16* Bt = (const u16*)Btv;

        auto stage = [&](int buf, int k0) {
            #pragma unroll
            for (int p = 0; p < NPB; ++p) {
                const int kp = k0 + p * 32;
                #pragma unroll
                for (int g = 0; g < BM / 16; ++g) {
                    if ((g & 3) != w) continue;    // group -> wave round-robin
                    gload_lds16(A + (size_t)(bm + g * 16 + srow) * K + kp + skq,
                                &As_[buf][p][g * 16 * 32]);
                }
                #pragma unroll
                for (int g = 0; g < BN / 16; ++g) {
                    if ((g & 3) != w) continue;
                    int rn = bn + g * 16 + srow;
                    if (GUARD) rn = (rn < N) ? rn : (N - 1);
                    gload_lds16(Bt + (size_t)rn * K + kp + skq,
                                &Bs_[buf][p][g * 16 * 32]);
                }
            }
        };

        stage(0, 0);
        __syncthreads();                 // drains vmcnt(0): buf0 ready
        int cur = 0;
        for (int k0 = 0; k0 + KB < K; k0 += KB) {
            stage(cur ^ 1, k0 + KB);     // issue next-tile loads FIRST
            compute(cur);                // MFMAs hide the load latency
            __syncthreads();
            cur ^= 1;
        }
        compute(cur);
    }

    const int cr = (ln >> 4) * 4;
    const int cc = ln & 15;
    #pragma unroll
    for (int mi = 0; mi < MI; ++mi) {
        const int row0 = bm + wm * (BM / 2) + mi * 16 + cr;
        #pragma unroll
        for (int ni = 0; ni < NI; ++ni) {
            const int col = bn + wn * (BN / 2) + ni * 16 + cc;
            #pragma unroll
            for (int r = 0; r < 4; ++r) {
                const int row = row0 + r;
                const float v = acc[mi][ni][r];
                if (PSPLIT) {
                    if (col < PB)
                        Cb[(size_t)row * PB + col] = f2bf(v);
                    else if (col < EPROJ)
                        Dt[(size_t)(col - PB) * MROWS + row] = v;   // TRANSPOSED [h][row]
                } else {
                    Cf[(size_t)row * N + col] = v;
                }
            }
        }
    }
}

// =====================================================================
// SSD phase 1 — 4-wave cooperative block per (b,h,chunk):
//   conv+silu via register sliding window over DIRECT global x reads;
//   exports conv'd X^T. La = cumsum(logdA);
//   Hc = (e^(La63-La_s) B)^T @ X (MFMA) -> stored bf16 (hb).
// =====================================================================
__global__ __launch_bounds__(256) void ssd_phase1(
    const u16* __restrict__ projb, const float* __restrict__ dtf,
    const float* __restrict__ cw, const float* __restrict__ cb,
    const float* __restrict__ A_log, const float* __restrict__ dt_bias,
    u16* __restrict__ hb, float* __restrict__ Pc, float* __restrict__ LaBuf,
    u32* __restrict__ xT)
{
    __shared__ u32 sBD[64 * 33];   // (e^(La63-La_s) B[s][n])^T : [n][s-pair]
    __shared__ u32 sXt[64 * 33];   // X^T: [p][s-pair]

    const int bid = blockIdx.x;               // ((b*16+h)*32 + c)
    const int c = bid & (NC - 1);
    const int h = (bid >> 5) & (NHEADS - 1);
    const int b = bid >> 9;
    const int tid = threadIdx.x;
    const int w = tid >> 6, ln = tid & 63;
    const int a = ln & 15, q = ln >> 4;
    const size_t r0 = (size_t)b * L_N + c * LC;

    // logdA + inclusive cumsum (redundant per wave; all waves identical)
    // dtf is [h][row] (transposed in gemm1 epilogue) -> coalesced 256 B read
    float dt = dtf[(size_t)h * MROWS + r0 + ln] + dt_bias[h];
    float sp = (dt > 15.f) ? dt : log1pf(__expf(dt));
    float La = sp * (-__expf(A_log[h]));
    #pragma unroll
    for (int d = 1; d < 64; d <<= 1) {
        float up = __shfl_up(La, d, 64);
        if (ln >= d) La += up;
    }
    if (w == 0) LaBuf[(size_t)bid * 64 + ln] = La;
    const float La63 = lane_bcast(La, 63);

    const int ch = h * 64 + ln;
    const float4 w4 = *(const float4*)(cw + ch * 4);
    const float bias = cb[ch];
    const u16* xcol = projb + OFF_XP + ch;     // column base for x reads
    const size_t bbase = (size_t)b * L_N;

    // rolling window: xr[0..2] = x at local rows (s-3, s-2, s-1); s0 = 16w
    float xr[3];
    #pragma unroll
    for (int i = 0; i < 3; ++i) {
        const int tl = c * LC + 16 * w - 3 + i;
        xr[i] = (tl >= 0) ? bf2f(xcol[(bbase + tl) * PB]) : 0.f;
    }

    // staging: wave w covers s-pairs [w*8, w*8+8); conv+silu inline
    #pragma unroll
    for (int j = 0; j < 8; ++j) {
        const int sp_ = w * 8 + j, s = sp_ * 2;
        const float xa = bf2f(xcol[(r0 + s) * PB]);
        const float xb = bf2f(xcol[(r0 + s + 1) * PB]);
        float a0 = bias, a1 = bias;
        a0 += xr[0] * w4.x; a0 += xr[1] * w4.y; a0 += xr[2] * w4.z; a0 += xa * w4.w;
        a1 += xr[1] * w4.x; a1 += xr[2] * w4.y; a1 += xa * w4.z;   a1 += xb * w4.w;
        xr[0] = xr[2]; xr[1] = xa; xr[2] = xb;
        const float x0 = silu_f(a0), x1 = silu_f(a1);
        const u32 xp = pack2(x0, x1);
        sXt[ln * 33 + sp_] = xp;
        xT[(size_t)bid * 2048 + sp_ * 64 + ln] = xp;   // export for phase3
        const float w0 = __expf(La63 - lane_bcast(La, s));
        const float w1 = __expf(La63 - lane_bcast(La, s + 1));
        const float b0 = bf2f(projb[(r0 + s) * PB + OFF_B + ln]) * w0;
        const float b1 = bf2f(projb[(r0 + s + 1) * PB + OFF_B + ln]) * w1;
        sBD[ln * 33 + sp_] = pack2(b0, b1);
    }
    __syncthreads();

    // MFMA: wave w computes output tile-row tm=w (rows n in [16w,16w+16))
    short8 af[2], bf[4][2];
    #pragma unroll
    for (int ks = 0; ks < 2; ++ks)
        af[ks] = frag_ld(sBD, w * 16 + a, ks * 32 + q * 8);
    #pragma unroll
    for (int tn = 0; tn < 4; ++tn)
        #pragma unroll
        for (int ks = 0; ks < 2; ++ks)
            bf[tn][ks] = frag_ld(sXt, tn * 16 + a, ks * 32 + q * 8);

    const floatx4 fzero = {0.f, 0.f, 0.f, 0.f};
    floatx4 acc[4];
    #pragma unroll
    for (int tn = 0; tn < 4; ++tn) {
        acc[tn] = fzero;
        #pragma unroll
        for (int ks = 0; ks < 2; ++ks)
            acc[tn] = __builtin_amdgcn_mfma_f32_16x16x32_bf16(
                af[ks], bf[tn][ks], acc[tn], 0, 0, 0);
    }

    u16* hp = hb + (size_t)bid * 4096;         // Hc bf16 [n][p]
    #pragma unroll
    for (int tn = 0; tn < 4; ++tn)
        #pragma unroll
        for (int r = 0; r < 4; ++r)
            hp[(w * 16 + q * 4 + r) * 64 + tn * 16 + a] = f2bf(acc[tn][r]);
    if (tid == 0) Pc[bid] = __expf(La63);
}

// =====================================================================
// SSD phase 2 — element-parallel inter-chunk carry over bf16 h-state
// (u32 pairs, f32 carries). Blocks [0,256): carry. Blocks [256,...):
// piggybacked W_out fp32->bf16 cast (fills the idle 2nd block/CU slot).
// =====================================================================
__global__ __launch_bounds__(256) void ssd_phase2(
    u32* __restrict__ hb32, const float* __restrict__ Pc,
    const float* __restrict__ wsrc, u16* __restrict__ wdst, int nw)
{
    const int bid = blockIdx.x;
    if (bid >= 256) {
        const int i = (bid - 256) * 256 + threadIdx.x;
        if (i < nw) {
            float4 v = ((const float4*)wsrc)[i];
            ushort4 o;
            o.x = f2bf(v.x); o.y = f2bf(v.y); o.z = f2bf(v.z); o.w = f2bf(v.w);
            ((ushort4*)wdst)[i] = o;
        }
        return;
    }

    const int bh = bid >> 3;
    const int e = (bid & 7) * 256 + threadIdx.x;    // u32 pair 0..2047
    const size_t base = (size_t)(bh * NC) * 2048 + e;

    u32 v[NC];
    #pragma unroll
    for (int c = 0; c < NC; ++c)
        v[c] = hb32[base + (size_t)c * 2048];

    float c0 = 0.f, c1 = 0.f;
    #pragma unroll
    for (int c = 0; c < NC; ++c) {
        const u32 cur = v[c];
        const float lo = bf2f((u16)cur), hi = bf2f((u16)(cur >> 16));
        v[c] = pack2(c0, c1);                  // h_start entering chunk c
        const float Pv = Pc[bh * NC + c];
        c0 = fmaf(Pv, c0, lo);
        c1 = fmaf(Pv, c1, hi);
    }

    #pragma unroll
    for (int c = 0; c < NC; ++c)
        hb32[base + (size_t)c * 2048] = v[c];
}

// =====================================================================
// SSD phase 3 — 4-wave cooperative block per (b,h,chunk):
//   X^T precomputed (phase1); h_start bf16 (phase2);
//   S^T = B @ C;  W[i][s] = S[i,s] e^(La_i-La_s) (s<=i)
//   Y = diag(e^La) C @ h_start^T + W @ X^T;  yz = Y * silu(z)
// =====================================================================
__global__ __launch_bounds__(256) void ssd_phase3(
    const u16* __restrict__ projb, const u32* __restrict__ xT,
    const u16* __restrict__ hb, const float* __restrict__ LaBuf,
    u16* __restrict__ yz)
{
    __shared__ char lds[34048];
    u32* sBW   = (u32*)lds;              // B natural, then W (aliased)
    u32* sC    = (u32*)(lds + 8448);     // C natural [i][n-pair]
    u32* sXt   = (u32*)(lds + 16896);    // X^T [p][s-pair]
    u32* sH    = (u32*)(lds + 25344);    // h_start^T [p][n-pair]
    float* sLaF = (float*)(lds + 33792); // La[64]
    float* sY  = (float*)(lds + 8448);   // f32 [i][p] 64x66, aliases sC+sXt (epilogue)

    const int bid = blockIdx.x;
    const int c = bid & (NC - 1);
    const int h = (bid >> 5) & (NHEADS - 1);
    const int b = bid >> 9;
    const int tid = threadIdx.x;
    const int w = tid >> 6, ln = tid & 63;
    const int a = ln & 15, q = ln >> 4;
    const int hw = ln >> 5, k32 = ln & 31;
    const size_t r0 = (size_t)b * L_N + c * LC;

    if (tid < 64) sLaF[tid] = LaBuf[(size_t)bid * 64 + tid];

    // single staging pass: B, C natural (raw copies); X^T copy; H^T pack
    const u16* hs = hb + (size_t)bid * 4096;
    #pragma unroll
    for (int j = 0; j < 8; ++j) {
        const int rp = w * 8 + j;
        const int row = rp * 2 + hw;
        sBW[row * 33 + k32] = *(const u32*)(projb + (r0 + row) * PB + OFF_B + 2 * k32);
        sC [row * 33 + k32] = *(const u32*)(projb + (r0 + row) * PB + OFF_C + 2 * k32);
        sXt[ln * 33 + rp] = xT[(size_t)bid * 2048 + rp * 64 + ln];
        sH [ln * 33 + rp] = (u32)hs[(2 * rp) * 64 + ln]
                          | ((u32)hs[(2 * rp + 1) * 64 + ln] << 16);
    }
    __syncthreads();

    const floatx4 fzero = {0.f, 0.f, 0.f, 0.f};

    // ---- m1: S^T tiles [tm][tn=w], tm<=w ----
    short8 cfr[2], bfr[4][2];
    #pragma unroll
    for (int ks = 0; ks < 2; ++ks)
        cfr[ks] = frag_ld(sC, w * 16 + a, ks * 32 + q * 8);
    #pragma unroll
    for (int tm = 0; tm < 4; ++tm)
        if (tm <= w)
            #pragma unroll
            for (int ks = 0; ks < 2; ++ks)
                bfr[tm][ks] = frag_ld(sBW, tm * 16 + a, ks * 32 + q * 8);
    floatx4 accS[4];
    #pragma unroll
    for (int tm = 0; tm < 4; ++tm) {
        if (tm > w) continue;
        accS[tm] = fzero;
        #pragma unroll
        for (int ks = 0; ks < 2; ++ks)
            accS[tm] = __builtin_amdgcn_mfma_f32_16x16x32_bf16(
                bfr[tm][ks], cfr[ks], accS[tm], 0, 0, 0);
    }
    __syncthreads();   // all waves done reading B before W overwrite

    // ---- build W rows i in [16w,16w+16) ----
    {
        const int i = w * 16 + a;
        const float Li = sLaF[i];
        #pragma unroll
        for (int tm = 0; tm < 4; ++tm) {
            const int d0 = i * 33 + tm * 8 + q * 2;
            if (tm > w) {
                sBW[d0] = 0; sBW[d0 + 1] = 0;
            } else {
                const float4 Ls = *(const float4*)(sLaF + tm * 16 + q * 4);
                float v[4];
                #pragma unroll
                for (int r = 0; r < 4; ++r) {
                    const int s = tm * 16 + q * 4 + r;
                    const float ww = (s <= i) ? __expf(Li - ((const float*)&Ls)[r]) : 0.f;
                    v[r] = accS[tm][r] * ww;
                }
                sBW[d0]     = pack2(v[0], v[1]);
                sBW[d0 + 1] = pack2(v[2], v[3]);
            }
        }
    }

    // ---- m4: accY = C @ h_start^T (row-tile w), scale rows by e^La_i ----
    short8 hfr[4][2];
    #pragma unroll
    for (int tp = 0; tp < 4; ++tp)
        #pragma unroll
        for (int ks = 0; ks < 2; ++ks)
            hfr[tp][ks] = frag_ld(sH, tp * 16 + a, ks * 32 + q * 8);
    floatx4 accY[4];
    #pragma unroll
    for (int tp = 0; tp < 4; ++tp) {
        accY[tp] = fzero;
        #pragma unroll
        for (int ks = 0; ks < 2; ++ks)
            accY[tp] = __builtin_amdgcn_mfma_f32_16x16x32_bf16(
                cfr[ks], hfr[tp][ks], accY[tp], 0, 0, 0);
    }
    {
        const float4 Ls = *(const float4*)(sLaF + w * 16 + q * 4);
        float e4[4];
        #pragma unroll
        for (int r = 0; r < 4; ++r) e4[r] = __expf(((const float*)&Ls)[r]);
        #pragma unroll
        for (int tp = 0; tp < 4; ++tp)
            #pragma unroll
            for (int r = 0; r < 4; ++r) accY[tp][r] *= e4[r];
    }

    // ---- m2: accY += W @ X^T (wave reads only its own W rows) ----
    short8 wfr[2], xfr[4][2];
    #pragma unroll
    for (int ks = 0; ks < 2; ++ks)
        wfr[ks] = frag_ld(sBW, w * 16 + a, ks * 32 + q * 8);
    #pragma unroll
    for (int tp = 0; tp < 4; ++tp)
        #pragma unroll
        for (int ks = 0; ks < 2; ++ks)
            xfr[tp][ks] = frag_ld(sXt, tp * 16 + a, ks * 32 + q * 8);
    #pragma unroll
    for (int tp = 0; tp < 4; ++tp)
        #pragma unroll
        for (int ks = 0; ks < 2; ++ks)
            accY[tp] = __builtin_amdgcn_mfma_f32_16x16x32_bf16(
                wfr[ks], xfr[tp][ks], accY[tp], 0, 0, 0);
    __syncthreads();   // all frag reads of sC/sXt done; safe to alias as sY

    // ---- epilogue: own-rows LDS round-trip, gate (bf16 z), bf16 store ----
    #pragma unroll
    for (int tp = 0; tp < 4; ++tp)
        #pragma unroll
        for (int r = 0; r < 4; ++r)
            sY[(w * 16 + q * 4 + r) * 66 + tp * 16 + a] = accY[tp][r];
    #pragma unroll
    for (int ii = 0; ii < 16; ++ii) {
        const int i = w * 16 + ii;
        const float y = sY[i * 66 + ln];
        const float z = bf2f(projb[(r0 + i) * PB + OFF_Z + h * 64 + ln]);
        yz[(r0 + i) * DINNER + h * 64 + ln] = f2bf(y * silu_f(z));
    }
}

// =====================================================================
extern "C" void kernel_launch(void* const* d_in, const int* in_sizes, int n_in,
                              void* d_out, int out_size, void* d_ws, size_t ws_size,
                              hipStream_t stream)
{
    const float* x       = (const float*)d_in[0];
    const float* W_in    = (const float*)d_in[1];
    const float* conv_w  = (const float*)d_in[2];
    const float* conv_b  = (const float*)d_in[3];
    const float* A_log   = (const float*)d_in[4];
    const float* dt_bias = (const float*)d_in[5];
    const float* W_out   = (const float*)d_in[6];
    float* out = (float*)d_out;

    // workspace layout (~59 MB; xbf/wibf slots retained but unused)
    u16*   projb = (u16*)d_ws;                                  // 4096*2176 bf16
    float* dtf   = (float*)(projb + (size_t)4096 * PB);         // 16*4096 f32 (TRANSPOSED [h][row])
    u16*   hb    = (u16*)(dtf + (size_t)4096 * 16);             // 1024*4096 bf16 (h-state)
    float* Pc    = (float*)(hb + (size_t)1024 * 4096);          // 1024
    float* LaBuf = Pc + 1024;                                   // 1024*64
    u16*   xbf   = (u16*)(LaBuf + 1024 * 64);                   // (unused)
    u16*   wibf  = xbf + (size_t)4096 * DMODEL;                 // (unused)
    u16*   wobf  = wibf + (size_t)EPROJ * DMODEL;               // 512*1024 bf16
    u16*   yzbf  = wobf + (size_t)DMODEL * DINNER;              // 4096*1024 bf16
    u32*   xT    = (u32*)(yzbf + (size_t)4096 * DINNER);        // 1024*2048 u32 (conv'd X^T)

    const int M = B_N * L_N;  // 4096
    const int n2 = DMODEL * DINNER / 4;

    // 1) in_proj: proj = x @ W_in^T (M=4096, N=2192, K=512) — fp32 inputs,
    //    inline cast (CVTIN) => no standalone cast kernel.
    //    BN=160 -> 448 blocks (all co-resident at 2/CU), dbuf NPB=2 (KB=64)
    gemm_mfma_bt<128, 160, 2, true, true, true><<<dim3(14, M / 128), 256, 0, stream>>>(
        x, W_in, nullptr, projb, dtf, M, EPROJ, DMODEL);

    // 2) SSD chunked scan (MFMA, 4-wave cooperative; conv in p1 via register
    //    sliding window; bf16 h-state pipeline; p3 consumes p1's X^T)
    ssd_phase1<<<B_N * NHEADS * NC, 256, 0, stream>>>(
        projb, dtf, conv_w, conv_b, A_log, dt_bias, hb, Pc, LaBuf, xT);
    ssd_phase2<<<256 + (n2 + 255) / 256, 256, 0, stream>>>(
        (u32*)hb, Pc, W_out, wobf, n2);
    ssd_phase3<<<B_N * NHEADS * NC, 256, 0, stream>>>(
        projb, xT, hb, LaBuf, yzbf);

    // 3) out_proj: out = yz @ W_out^T (M=4096, N=512, K=1024),
    //    512 blocks (2/CU), dbuf NPB=4 (KB=128) -> 8 overlapped K-tiles
    gemm_mfma_bt<64, 64, 4, false, false, false><<<dim3(DMODEL / 64, M / 64), 256, 0, stream>>>(
        yzbf, wobf, out, nullptr, nullptr, M, DMODEL, DINNER);
}

// Round 5
// 131.066 us; speedup vs baseline: 2.5826x; 1.0168x over previous
//
#include <hip/hip_runtime.h>
#include <cstdint>
#include <cstddef>

// ---- problem constants ----
#define B_N     2
#define L_N     2048
#define DMODEL  512
#define DINNER  1024
#define DSTATE  64
#define NHEADS  16
#define EPROJ   2192      // 2*DINNER + 2*DSTATE + NHEADS
#define PB      2176      // bf16 proj row stride (z,x,B,C)
#define OFF_Z   0
#define OFF_XP  1024
#define OFF_B   2048
#define OFF_C   2112
#define LC      64        // scan chunk length (= matmul tile)
#define NC      32        // L_N / LC
#define MROWS   4096      // B_N * L_N

typedef unsigned short u16;
typedef unsigned int   u32;
typedef __attribute__((ext_vector_type(8))) short short8;   // 8 bf16 (4 VGPRs)
typedef __attribute__((ext_vector_type(4))) float floatx4;  // MFMA acc

__device__ __forceinline__ float silu_f(float v) { return v / (1.f + __expf(-v)); }

__device__ __forceinline__ u16 f2bf(float f) {
    union { float f; uint32_t u; } v; v.f = f;
    uint32_t r = (v.u + 0x7FFFu + ((v.u >> 16) & 1u)) >> 16;  // RNE
    return (u16)r;
}

__device__ __forceinline__ float bf2f(u16 b) {
    union { u32 u; float f; } v; v.u = (u32)b << 16; return v.f;
}

__device__ __forceinline__ u32 pack2(float lo, float hi) {
    return (u32)f2bf(lo) | ((u32)f2bf(hi) << 16);
}

// HW packed f32->bf16 (RNE), 2 elems/instr — for gemm1 inline cast staging
__device__ __forceinline__ u32 cvtpk(float lo, float hi) {
    u32 r;
    asm("v_cvt_pk_bf16_f32 %0, %1, %2" : "=v"(r) : "v"(lo), "v"(hi));
    return r;
}

__device__ __forceinline__ uint4 pk8(const float4& a, const float4& b) {
    uint4 o;
    o.x = cvtpk(a.x, a.y); o.y = cvtpk(a.z, a.w);
    o.z = cvtpk(b.x, b.y); o.w = cvtpk(b.z, b.w);
    return o;
}

__device__ __forceinline__ float lane_bcast(float v, int n) {
    union { float f; uint32_t u; } a, b;
    a.f = v;
    b.u = __builtin_amdgcn_readlane(a.u, n);
    return b.f;
}

// read bf16 fragment A[row][k0..k0+7] from pair-packed LDS tile (stride 33 dwords)
__device__ __forceinline__ short8 frag_ld(const u32* s, int row, int k0) {
    const u32* q = s + row * 33 + (k0 >> 1);
    union { u32 u[4]; short8 v; } r;
    r.u[0] = q[0]; r.u[1] = q[1]; r.u[2] = q[2]; r.u[3] = q[3];
    return r.v;
}

__device__ __forceinline__ void gload_lds16(const u16* g, u16* s) {
    __builtin_amdgcn_global_load_lds(
        (const __attribute__((address_space(1))) void*)g,
        (__attribute__((address_space(3))) void*)s,
        16, 0, 0);
}

// =====================================================================
// bf16 MFMA GEMM, 2-phase double-buffered, XCD-rectangle-swizzled.
//   C = A[M,K] @ Bt[N,K]^T.  4 waves as 2x2; wave tile (BM/2)x(BN/2).
// Grid is FLAT (NBX*NBY blocks). HW dispatch: block i -> XCD i%8.
// Blocks on XCD k form a RBX x RBY tile-rectangle => each XCD's L2
// holds only its rectangle's A/B panels (T1: kills 8x panel refetch).
//   bx = (k % (NBX/RBX))*RBX + j%RBX,  by = (k / (NBX/RBX))*RBY + j/RBX
//   (k = i&7, j = i>>3; requires NBX%RBX==0, NBY%RBY==0,
//    (NBX/RBX)*(NBY/RBY)==8, grid = NBX*NBY, divisible by 8 => bijective)
// K % (32*NPB) == 0 assumed. PSPLIT: col<2176 -> bf16 projb; else f32 dtT
// (TRANSPOSED [h][row] so phase1 reads dt coalesced).
// CVTIN: A/Bt are fp32; staging inline-casts to bf16 (T14 split: issue
// loads -> compute(cur) -> cvt+ds_write -> barrier).
// LDS: 2*NPB*(BM+BN)*64 B  (gemm1 NPB=2: 73.7 KB; gemm2 NPB=4: 65.5 KB —
// both exactly 2 blocks/CU).
// =====================================================================
template<int BM, int BN, int NPB, bool GUARD, bool PSPLIT, bool CVTIN,
         int NBX, int RBX, int RBY>
__global__ __launch_bounds__(256, 2) void gemm_mfma_bt(
    const void* __restrict__ Av, const void* __restrict__ Btv,
    float* __restrict__ Cf, u16* __restrict__ Cb, float* __restrict__ Dt,
    int M, int N, int K)
{
    constexpr int MI = BM / 32;
    constexpr int NI = BN / 32;
    constexpr int KB = 32 * NPB;
    constexpr int NGA = BM / 64;              // A-groups per wave per panel
    constexpr int NGB = (BN / 16 + 3) / 4;    // B-groups per wave per panel (tail predicated)
    constexpr int XC  = NBX / RBX;            // xcd-grid columns
    __shared__ u16 As_[2][NPB][BM * 32];
    __shared__ u16 Bs_[2][NPB][BN * 32];

    const int tid = threadIdx.x;
    const int w   = tid >> 6;
    const int ln  = tid & 63;
    const int wm  = w >> 1, wn = w & 1;

    // ---- XCD-rectangle block swizzle (bijective) ----
    const int k  = blockIdx.x & 7;
    const int j  = blockIdx.x >> 3;
    const int bx = (k % XC) * RBX + (j % RBX);
    const int by = (k / XC) * RBY + (j / RBX);
    const int bm = by * BM;
    const int bn = bx * BN;

    const int srow = ln >> 2;          // 16 rows per wave-load group
    const int skq  = (ln & 3) * 8;
    const int fr = ln & 15;
    const int fq = (ln >> 4) * 8;

    floatx4 acc[MI][NI];
    const floatx4 fzero = {0.f, 0.f, 0.f, 0.f};
    #pragma unroll
    for (int mi = 0; mi < MI; ++mi)
        #pragma unroll
        for (int ni = 0; ni < NI; ++ni) acc[mi][ni] = fzero;

    auto compute = [&](int buf) {
        #pragma unroll
        for (int p = 0; p < NPB; ++p) {
            short8 af[MI], bfv[NI];
            #pragma unroll
            for (int mi = 0; mi < MI; ++mi)
                af[mi] = *(const short8*)&As_[buf][p][(wm * (BM / 2) + mi * 16 + fr) * 32 + fq];
            #pragma unroll
            for (int ni = 0; ni < NI; ++ni)
                bfv[ni] = *(const short8*)&Bs_[buf][p][(wn * (BN / 2) + ni * 16 + fr) * 32 + fq];
            #pragma unroll
            for (int mi = 0; mi < MI; ++mi)
                #pragma unroll
                for (int ni = 0; ni < NI; ++ni)
                    acc[mi][ni] = __builtin_amdgcn_mfma_f32_16x16x32_bf16(
                        af[mi], bfv[ni], acc[mi][ni], 0, 0, 0);
        }
    };

    if constexpr (CVTIN) {
        // ---------- fp32 inputs, inline-cast reg staging ----------
        const float* A  = (const float*)Av;
        const float* Bt = (const float*)Btv;
        float4 hA[NPB][NGA][2];
        float4 hB[NPB][NGB][2];

        auto ld = [&](int k0) {           // issue f32 loads into hold regs
            #pragma unroll
            for (int p = 0; p < NPB; ++p) {
                const int kp = k0 + p * 32;
                #pragma unroll
                for (int gi = 0; gi < NGA; ++gi) {
                    const int g = gi * 4 + w;
                    const float* s = A + (size_t)(bm + g * 16 + srow) * K + kp + skq;
                    hA[p][gi][0] = *(const float4*)s;
                    hA[p][gi][1] = *(const float4*)(s + 4);
                }
                #pragma unroll
                for (int gi = 0; gi < NGB; ++gi) {
                    const int g = gi * 4 + w;
                    if (g < BN / 16) {
                        int rn = bn + g * 16 + srow;
                        if (GUARD) rn = (rn < N) ? rn : (N - 1);
                        const float* s = Bt + (size_t)rn * K + kp + skq;
                        hB[p][gi][0] = *(const float4*)s;
                        hB[p][gi][1] = *(const float4*)(s + 4);
                    }
                }
            }
        };
        auto st = [&](int buf) {          // cvt + LDS write (waits loads here)
            #pragma unroll
            for (int p = 0; p < NPB; ++p) {
                #pragma unroll
                for (int gi = 0; gi < NGA; ++gi) {
                    const int g = gi * 4 + w;
                    ((uint4*)&As_[buf][p][g * 16 * 32])[ln] =
                        pk8(hA[p][gi][0], hA[p][gi][1]);
                }
                #pragma unroll
                for (int gi = 0; gi < NGB; ++gi) {
                    const int g = gi * 4 + w;
                    if (g < BN / 16)
                        ((uint4*)&Bs_[buf][p][g * 16 * 32])[ln] =
                            pk8(hB[p][gi][0], hB[p][gi][1]);
                }
            }
        };

        ld(0); st(0);
        __syncthreads();
        int cur = 0;
        for (int k0 = 0; k0 + KB < K; k0 += KB) {
            ld(k0 + KB);                 // issue next-tile f32 loads
            compute(cur);                // MFMAs hide the load latency
            st(cur ^ 1);                 // cvt+write after compute (T14)
            __syncthreads();
            cur ^= 1;
        }
        compute(cur);
    } else {
        // ---------- bf16 inputs, global_load_lds staging ----------
        const u16* A  = (const u16*)Av;
        const u16* Bt = (const u16*)Btv;

        auto stage = [&](int buf, int k0) {
            #pragma unroll
            for (int p = 0; p < NPB; ++p) {
                const int kp = k0 + p * 32;
                #pragma unroll
                for (int g = 0; g < BM / 16; ++g) {
                    if ((g & 3) != w) continue;    // group -> wave round-robin
                    gload_lds16(A + (size_t)(bm + g * 16 + srow) * K + kp + skq,
                                &As_[buf][p][g * 16 * 32]);
                }
                #pragma unroll
                for (int g = 0; g < BN / 16; ++g) {
                    if ((g & 3) != w) continue;
                    int rn = bn + g * 16 + srow;
                    if (GUARD) rn = (rn < N) ? rn : (N - 1);
                    gload_lds16(Bt + (size_t)rn * K + kp + skq,
                                &Bs_[buf][p][g * 16 * 32]);
                }
            }
        };

        stage(0, 0);
        __syncthreads();                 // drains vmcnt(0): buf0 ready
        int cur = 0;
        for (int k0 = 0; k0 + KB < K; k0 += KB) {
            stage(cur ^ 1, k0 + KB);     // issue next-tile loads FIRST
            compute(cur);                // MFMAs hide the load latency
            __syncthreads();
            cur ^= 1;
        }
        compute(cur);
    }

    const int cr = (ln >> 4) * 4;
    const int cc = ln & 15;
    #pragma unroll
    for (int mi = 0; mi < MI; ++mi) {
        const int row0 = bm + wm * (BM / 2) + mi * 16 + cr;
        #pragma unroll
        for (int ni = 0; ni < NI; ++ni) {
            const int col = bn + wn * (BN / 2) + ni * 16 + cc;
            #pragma unroll
            for (int r = 0; r < 4; ++r) {
                const int row = row0 + r;
                const float v = acc[mi][ni][r];
                if (PSPLIT) {
                    if (col < PB)
                        Cb[(size_t)row * PB + col] = f2bf(v);
                    else if (col < EPROJ)
                        Dt[(size_t)(col - PB) * MROWS + row] = v;   // TRANSPOSED [h][row]
                } else {
                    Cf[(size_t)row * N + col] = v;
                }
            }
        }
    }
}

// =====================================================================
// SSD phase 1 — 4-wave cooperative block per (b,h,chunk):
//   conv+silu via register sliding window over DIRECT global x reads;
//   exports conv'd X^T. La = cumsum(logdA);
//   Hc = (e^(La63-La_s) B)^T @ X (MFMA) -> stored bf16 (hb).
// (blocks sharing B/C rows — same (b,c), varying h — are 32 apart,
//  32%8==0 => same XCD already: no swizzle needed here.)
// =====================================================================
__global__ __launch_bounds__(256) void ssd_phase1(
    const u16* __restrict__ projb, const float* __restrict__ dtf,
    const float* __restrict__ cw, const float* __restrict__ cb,
    const float* __restrict__ A_log, const float* __restrict__ dt_bias,
    u16* __restrict__ hb, float* __restrict__ Pc, float* __restrict__ LaBuf,
    u32* __restrict__ xT)
{
    __shared__ u32 sBD[64 * 33];   // (e^(La63-La_s) B[s][n])^T : [n][s-pair]
    __shared__ u32 sXt[64 * 33];   // X^T: [p][s-pair]

    const int bid = blockIdx.x;               // ((b*16+h)*32 + c)
    const int c = bid & (NC - 1);
    const int h = (bid >> 5) & (NHEADS - 1);
    const int b = bid >> 9;
    const int tid = threadIdx.x;
    const int w = tid >> 6, ln = tid & 63;
    const int a = ln & 15, q = ln >> 4;
    const size_t r0 = (size_t)b * L_N + c * LC;

    // logdA + inclusive cumsum (redundant per wave; all waves identical)
    // dtf is [h][row] (transposed in gemm1 epilogue) -> coalesced 256 B read
    float dt = dtf[(size_t)h * MROWS + r0 + ln] + dt_bias[h];
    float sp = (dt > 15.f) ? dt : log1pf(__expf(dt));
    float La = sp * (-__expf(A_log[h]));
    #pragma unroll
    for (int d = 1; d < 64; d <<= 1) {
        float up = __shfl_up(La, d, 64);
        if (ln >= d) La += up;
    }
    if (w == 0) LaBuf[(size_t)bid * 64 + ln] = La;
    const float La63 = lane_bcast(La, 63);

    const int ch = h * 64 + ln;
    const float4 w4 = *(const float4*)(cw + ch * 4);
    const float bias = cb[ch];
    const u16* xcol = projb + OFF_XP + ch;     // column base for x reads
    const size_t bbase = (size_t)b * L_N;

    // rolling window: xr[0..2] = x at local rows (s-3, s-2, s-1); s0 = 16w
    float xr[3];
    #pragma unroll
    for (int i = 0; i < 3; ++i) {
        const int tl = c * LC + 16 * w - 3 + i;
        xr[i] = (tl >= 0) ? bf2f(xcol[(bbase + tl) * PB]) : 0.f;
    }

    // staging: wave w covers s-pairs [w*8, w*8+8); conv+silu inline
    #pragma unroll
    for (int j = 0; j < 8; ++j) {
        const int sp_ = w * 8 + j, s = sp_ * 2;
        const float xa = bf2f(xcol[(r0 + s) * PB]);
        const float xb = bf2f(xcol[(r0 + s + 1) * PB]);
        float a0 = bias, a1 = bias;
        a0 += xr[0] * w4.x; a0 += xr[1] * w4.y; a0 += xr[2] * w4.z; a0 += xa * w4.w;
        a1 += xr[1] * w4.x; a1 += xr[2] * w4.y; a1 += xa * w4.z;   a1 += xb * w4.w;
        xr[0] = xr[2]; xr[1] = xa; xr[2] = xb;
        const float x0 = silu_f(a0), x1 = silu_f(a1);
        const u32 xp = pack2(x0, x1);
        sXt[ln * 33 + sp_] = xp;
        xT[(size_t)bid * 2048 + sp_ * 64 + ln] = xp;   // export for phase3
        const float w0 = __expf(La63 - lane_bcast(La, s));
        const float w1 = __expf(La63 - lane_bcast(La, s + 1));
        const float b0 = bf2f(projb[(r0 + s) * PB + OFF_B + ln]) * w0;
        const float b1 = bf2f(projb[(r0 + s + 1) * PB + OFF_B + ln]) * w1;
        sBD[ln * 33 + sp_] = pack2(b0, b1);
    }
    __syncthreads();

    // MFMA: wave w computes output tile-row tm=w (rows n in [16w,16w+16))
    short8 af[2], bf[4][2];
    #pragma unroll
    for (int ks = 0; ks < 2; ++ks)
        af[ks] = frag_ld(sBD, w * 16 + a, ks * 32 + q * 8);
    #pragma unroll
    for (int tn = 0; tn < 4; ++tn)
        #pragma unroll
        for (int ks = 0; ks < 2; ++ks)
            bf[tn][ks] = frag_ld(sXt, tn * 16 + a, ks * 32 + q * 8);

    const floatx4 fzero = {0.f, 0.f, 0.f, 0.f};
    floatx4 acc[4];
    #pragma unroll
    for (int tn = 0; tn < 4; ++tn) {
        acc[tn] = fzero;
        #pragma unroll
        for (int ks = 0; ks < 2; ++ks)
            acc[tn] = __builtin_amdgcn_mfma_f32_16x16x32_bf16(
                af[ks], bf[tn][ks], acc[tn], 0, 0, 0);
    }

    u16* hp = hb + (size_t)bid * 4096;         // Hc bf16 [n][p]
    #pragma unroll
    for (int tn = 0; tn < 4; ++tn)
        #pragma unroll
        for (int r = 0; r < 4; ++r)
            hp[(w * 16 + q * 4 + r) * 64 + tn * 16 + a] = f2bf(acc[tn][r]);
    if (tid == 0) Pc[bid] = __expf(La63);
}

// =====================================================================
// SSD phase 2 — element-parallel inter-chunk carry over bf16 h-state
// (u32 pairs, f32 carries). Blocks [0,256): carry. Blocks [256,...):
// piggybacked W_out fp32->bf16 cast (fills the idle 2nd block/CU slot).
// =====================================================================
__global__ __launch_bounds__(256) void ssd_phase2(
    u32* __restrict__ hb32, const float* __restrict__ Pc,
    const float* __restrict__ wsrc, u16* __restrict__ wdst, int nw)
{
    const int bid = blockIdx.x;
    if (bid >= 256) {
        const int i = (bid - 256) * 256 + threadIdx.x;
        if (i < nw) {
            float4 v = ((const float4*)wsrc)[i];
            ushort4 o;
            o.x = f2bf(v.x); o.y = f2bf(v.y); o.z = f2bf(v.z); o.w = f2bf(v.w);
            ((ushort4*)wdst)[i] = o;
        }
        return;
    }

    const int bh = bid >> 3;
    const int e = (bid & 7) * 256 + threadIdx.x;    // u32 pair 0..2047
    const size_t base = (size_t)(bh * NC) * 2048 + e;

    u32 v[NC];
    #pragma unroll
    for (int c = 0; c < NC; ++c)
        v[c] = hb32[base + (size_t)c * 2048];

    float c0 = 0.f, c1 = 0.f;
    #pragma unroll
    for (int c = 0; c < NC; ++c) {
        const u32 cur = v[c];
        const float lo = bf2f((u16)cur), hi = bf2f((u16)(cur >> 16));
        v[c] = pack2(c0, c1);                  // h_start entering chunk c
        const float Pv = Pc[bh * NC + c];
        c0 = fmaf(Pv, c0, lo);
        c1 = fmaf(Pv, c1, hi);
    }

    #pragma unroll
    for (int c = 0; c < NC; ++c)
        hb32[base + (size_t)c * 2048] = v[c];
}

// =====================================================================
// SSD phase 3 — 4-wave cooperative block per (b,h,chunk):
//   X^T precomputed (phase1); h_start bf16 (phase2);
//   S^T = B @ C;  W[i][s] = S[i,s] e^(La_i-La_s) (s<=i)
//   Y = diag(e^La) C @ h_start^T + W @ X^T;  yz = Y * silu(z)
// =====================================================================
__global__ __launch_bounds__(256) void ssd_phase3(
    const u16* __restrict__ projb, const u32* __restrict__ xT,
    const u16* __restrict__ hb, const float* __restrict__ LaBuf,
    u16* __restrict__ yz)
{
    __shared__ char lds[34048];
    u32* sBW   = (u32*)lds;              // B natural, then W (aliased)
    u32* sC    = (u32*)(lds + 8448);     // C natural [i][n-pair]
    u32* sXt   = (u32*)(lds + 16896);    // X^T [p][s-pair]
    u32* sH    = (u32*)(lds + 25344);    // h_start^T [p][n-pair]
    float* sLaF = (float*)(lds + 33792); // La[64]
    float* sY  = (float*)(lds + 8448);   // f32 [i][p] 64x66, aliases sC+sXt (epilogue)

    const int bid = blockIdx.x;
    const int c = bid & (NC - 1);
    const int h = (bid >> 5) & (NHEADS - 1);
    const int b = bid >> 9;
    const int tid = threadIdx.x;
    const int w = tid >> 6, ln = tid & 63;
    const int a = ln & 15, q = ln >> 4;
    const int hw = ln >> 5, k32 = ln & 31;
    const size_t r0 = (size_t)b * L_N + c * LC;

    if (tid < 64) sLaF[tid] = LaBuf[(size_t)bid * 64 + tid];

    // single staging pass: B, C natural (raw copies); X^T copy; H^T pack
    const u16* hs = hb + (size_t)bid * 4096;
    #pragma unroll
    for (int j = 0; j < 8; ++j) {
        const int rp = w * 8 + j;
        const int row = rp * 2 + hw;
        sBW[row * 33 + k32] = *(const u32*)(projb + (r0 + row) * PB + OFF_B + 2 * k32);
        sC [row * 33 + k32] = *(const u32*)(projb + (r0 + row) * PB + OFF_C + 2 * k32);
        sXt[ln * 33 + rp] = xT[(size_t)bid * 2048 + rp * 64 + ln];
        sH [ln * 33 + rp] = (u32)hs[(2 * rp) * 64 + ln]
                          | ((u32)hs[(2 * rp + 1) * 64 + ln] << 16);
    }
    __syncthreads();

    const floatx4 fzero = {0.f, 0.f, 0.f, 0.f};

    // ---- m1: S^T tiles [tm][tn=w], tm<=w ----
    short8 cfr[2], bfr[4][2];
    #pragma unroll
    for (int ks = 0; ks < 2; ++ks)
        cfr[ks] = frag_ld(sC, w * 16 + a, ks * 32 + q * 8);
    #pragma unroll
    for (int tm = 0; tm < 4; ++tm)
        if (tm <= w)
            #pragma unroll
            for (int ks = 0; ks < 2; ++ks)
                bfr[tm][ks] = frag_ld(sBW, tm * 16 + a, ks * 32 + q * 8);
    floatx4 accS[4];
    #pragma unroll
    for (int tm = 0; tm < 4; ++tm) {
        if (tm > w) continue;
        accS[tm] = fzero;
        #pragma unroll
        for (int ks = 0; ks < 2; ++ks)
            accS[tm] = __builtin_amdgcn_mfma_f32_16x16x32_bf16(
                bfr[tm][ks], cfr[ks], accS[tm], 0, 0, 0);
    }
    __syncthreads();   // all waves done reading B before W overwrite

    // ---- build W rows i in [16w,16w+16) ----
    {
        const int i = w * 16 + a;
        const float Li = sLaF[i];
        #pragma unroll
        for (int tm = 0; tm < 4; ++tm) {
            const int d0 = i * 33 + tm * 8 + q * 2;
            if (tm > w) {
                sBW[d0] = 0; sBW[d0 + 1] = 0;
            } else {
                const float4 Ls = *(const float4*)(sLaF + tm * 16 + q * 4);
                float v[4];
                #pragma unroll
                for (int r = 0; r < 4; ++r) {
                    const int s = tm * 16 + q * 4 + r;
                    const float ww = (s <= i) ? __expf(Li - ((const float*)&Ls)[r]) : 0.f;
                    v[r] = accS[tm][r] * ww;
                }
                sBW[d0]     = pack2(v[0], v[1]);
                sBW[d0 + 1] = pack2(v[2], v[3]);
            }
        }
    }

    // ---- m4: accY = C @ h_start^T (row-tile w), scale rows by e^La_i ----
    short8 hfr[4][2];
    #pragma unroll
    for (int tp = 0; tp < 4; ++tp)
        #pragma unroll
        for (int ks = 0; ks < 2; ++ks)
            hfr[tp][ks] = frag_ld(sH, tp * 16 + a, ks * 32 + q * 8);
    floatx4 accY[4];
    #pragma unroll
    for (int tp = 0; tp < 4; ++tp) {
        accY[tp] = fzero;
        #pragma unroll
        for (int ks = 0; ks < 2; ++ks)
            accY[tp] = __builtin_amdgcn_mfma_f32_16x16x32_bf16(
                cfr[ks], hfr[tp][ks], accY[tp], 0, 0, 0);
    }
    {
        const float4 Ls = *(const float4*)(sLaF + w * 16 + q * 4);
        float e4[4];
        #pragma unroll
        for (int r = 0; r < 4; ++r) e4[r] = __expf(((const float*)&Ls)[r]);
        #pragma unroll
        for (int tp = 0; tp < 4; ++tp)
            #pragma unroll
            for (int r = 0; r < 4; ++r) accY[tp][r] *= e4[r];
    }

    // ---- m2: accY += W @ X^T (wave reads only its own W rows) ----
    short8 wfr[2], xfr[4][2];
    #pragma unroll
    for (int ks = 0; ks < 2; ++ks)
        wfr[ks] = frag_ld(sBW, w * 16 + a, ks * 32 + q * 8);
    #pragma unroll
    for (int tp = 0; tp < 4; ++tp)
        #pragma unroll
        for (int ks = 0; ks < 2; ++ks)
            xfr[tp][ks] = frag_ld(sXt, tp * 16 + a, ks * 32 + q * 8);
    #pragma unroll
    for (int tp = 0; tp < 4; ++tp)
        #pragma unroll
        for (int ks = 0; ks < 2; ++ks)
            accY[tp] = __builtin_amdgcn_mfma_f32_16x16x32_bf16(
                wfr[ks], xfr[tp][ks], accY[tp], 0, 0, 0);
    __syncthreads();   // all frag reads of sC/sXt done; safe to alias as sY

    // ---- epilogue: own-rows LDS round-trip, gate (bf16 z), bf16 store ----
    #pragma unroll
    for (int tp = 0; tp < 4; ++tp)
        #pragma unroll
        for (int r = 0; r < 4; ++r)
            sY[(w * 16 + q * 4 + r) * 66 + tp * 16 + a] = accY[tp][r];
    #pragma unroll
    for (int ii = 0; ii < 16; ++ii) {
        const int i = w * 16 + ii;
        const float y = sY[i * 66 + ln];
        const float z = bf2f(projb[(r0 + i) * PB + OFF_Z + h * 64 + ln]);
        yz[(r0 + i) * DINNER + h * 64 + ln] = f2bf(y * silu_f(z));
    }
}

// =====================================================================
extern "C" void kernel_launch(void* const* d_in, const int* in_sizes, int n_in,
                              void* d_out, int out_size, void* d_ws, size_t ws_size,
                              hipStream_t stream)
{
    const float* x       = (const float*)d_in[0];
    const float* W_in    = (const float*)d_in[1];
    const float* conv_w  = (const float*)d_in[2];
    const float* conv_b  = (const float*)d_in[3];
    const float* A_log   = (const float*)d_in[4];
    const float* dt_bias = (const float*)d_in[5];
    const float* W_out   = (const float*)d_in[6];
    float* out = (float*)d_out;

    // workspace layout (~59 MB; xbf/wibf slots retained but unused)
    u16*   projb = (u16*)d_ws;                                  // 4096*2176 bf16
    float* dtf   = (float*)(projb + (size_t)4096 * PB);         // 16*4096 f32 (TRANSPOSED [h][row])
    u16*   hb    = (u16*)(dtf + (size_t)4096 * 16);             // 1024*4096 bf16 (h-state)
    float* Pc    = (float*)(hb + (size_t)1024 * 4096);          // 1024
    float* LaBuf = Pc + 1024;                                   // 1024*64
    u16*   xbf   = (u16*)(LaBuf + 1024 * 64);                   // (unused)
    u16*   wibf  = xbf + (size_t)4096 * DMODEL;                 // (unused)
    u16*   wobf  = wibf + (size_t)EPROJ * DMODEL;               // 512*1024 bf16
    u16*   yzbf  = wobf + (size_t)DMODEL * DINNER;              // 4096*1024 bf16
    u32*   xT    = (u32*)(yzbf + (size_t)4096 * DINNER);        // 1024*2048 u32 (conv'd X^T)

    const int M = B_N * L_N;  // 4096
    const int n2 = DMODEL * DINNER / 4;

    // 1) in_proj: proj = x @ W_in^T (M=4096, N=2192, K=512) — fp32 inputs,
    //    inline cast (CVTIN). Flat 448-block grid; XCD rect 7bx x 8by
    //    (per-XCD working set: 7 W_in panels + 8 x panels ~= 4.25 MB ~ L2).
    gemm_mfma_bt<128, 160, 2, true, true, true, 14, 7, 8>
        <<<dim3(14 * (M / 128)), 256, 0, stream>>>(
        x, W_in, nullptr, projb, dtf, M, EPROJ, DMODEL);

    // 2) SSD chunked scan (MFMA, 4-wave cooperative; conv in p1 via register
    //    sliding window; bf16 h-state pipeline; p3 consumes p1's X^T)
    ssd_phase1<<<B_N * NHEADS * NC, 256, 0, stream>>>(
        projb, dtf, conv_w, conv_b, A_log, dt_bias, hb, Pc, LaBuf, xT);
    ssd_phase2<<<256 + (n2 + 255) / 256, 256, 0, stream>>>(
        (u32*)hb, Pc, W_out, wobf, n2);
    ssd_phase3<<<B_N * NHEADS * NC, 256, 0, stream>>>(
        projb, xT, hb, LaBuf, yzbf);

    // 3) out_proj: out = yz @ W_out^T (M=4096, N=512, K=1024) — bf16,
    //    gload_lds staging. Flat 512-block grid; XCD rect 8bx x 8by
    //    (per-XCD working set: whole wobf 1 MB + 8 yz panels 1 MB -> L2-hot).
    gemm_mfma_bt<64, 64, 4, false, false, false, 8, 8, 8>
        <<<dim3((DMODEL / 64) * (M / 64)), 256, 0, stream>>>(
        yzbf, wobf, out, nullptr, nullptr, M, DMODEL, DINNER);
}